// Round 1
// baseline (838.357 us; speedup 1.0000x reference)
//
#include <hip/hip_runtime.h>

// Problem constants (B,H,W,C = 8,64,64,256; S = H*W)
#define NB   8
#define SS   4096
#define CC   256
#define NG   32
#define CPG  8
#define EPSV 1e-6f
#define MTOT (NB * SS)   // 32768 rows

typedef short bf16x8 __attribute__((ext_vector_type(8)));
typedef float f32x4  __attribute__((ext_vector_type(4)));

__device__ __forceinline__ unsigned short f2bf(float f) {
  unsigned int u = __builtin_bit_cast(unsigned int, f);
  u = (u + 0x7FFFu + ((u >> 16) & 1u)) >> 16;
  return (unsigned short)u;
}

// ---------------- GroupNorm: stats (block per (b, group)) ----------------
__global__ __launch_bounds__(256) void gn_stats_kernel(const float* __restrict__ x,
                                                       float* __restrict__ stats) {
  int bg = blockIdx.x;           // 0..255
  int b = bg >> 5, g = bg & 31;
  const float* base = x + (size_t)b * SS * CC + g * CPG;
  float s = 0.f, ss = 0.f;
  for (int pos = threadIdx.x; pos < SS; pos += 256) {
    const float4* p = (const float4*)(base + (size_t)pos * CC);
    float4 a = p[0];
    float4 c = p[1];
    s  += (a.x + a.y) + (a.z + a.w) + (c.x + c.y) + (c.z + c.w);
    ss += (a.x*a.x + a.y*a.y) + (a.z*a.z + a.w*a.w)
        + (c.x*c.x + c.y*c.y) + (c.z*c.z + c.w*c.w);
  }
#pragma unroll
  for (int off = 32; off >= 1; off >>= 1) {
    s  += __shfl_xor(s, off);
    ss += __shfl_xor(ss, off);
  }
  __shared__ float rs[4], rss[4];
  int wv = threadIdx.x >> 6;
  if ((threadIdx.x & 63) == 0) { rs[wv] = s; rss[wv] = ss; }
  __syncthreads();
  if (threadIdx.x == 0) {
    float ts  = (rs[0] + rs[1]) + (rs[2] + rs[3]);
    float tss = (rss[0] + rss[1]) + (rss[2] + rss[3]);
    const float inv = 1.f / (float)(SS * CPG);
    float mean = ts * inv;
    float var  = tss * inv - mean * mean;
    stats[bg * 2]     = mean;
    stats[bg * 2 + 1] = rsqrtf(var + EPSV);
  }
}

// ---------------- GroupNorm: normalize -> hn (bf16) ----------------
__global__ __launch_bounds__(256) void gn_norm_kernel(const float* __restrict__ x,
                                                      const float* __restrict__ stats,
                                                      const float* __restrict__ gamma,
                                                      const float* __restrict__ beta,
                                                      unsigned short* __restrict__ hn) {
  int i4 = blockIdx.x * 256 + threadIdx.x;      // each handles 4 channels
  int c4 = (i4 & 63) * 4;                       // 64 float4 per row
  size_t row = (size_t)(i4 >> 6);               // b*S + s
  int b = (int)(row >> 12);
  int sidx = (b * NG + (c4 >> 3)) * 2;
  float mean = stats[sidx], rstd = stats[sidx + 1];
  float4 v  = *(const float4*)(x + row * CC + c4);
  float4 ga = *(const float4*)(gamma + c4);
  float4 be = *(const float4*)(beta + c4);
  ushort4 o;
  o.x = f2bf((v.x - mean) * rstd * ga.x + be.x);
  o.y = f2bf((v.y - mean) * rstd * ga.y + be.y);
  o.z = f2bf((v.z - mean) * rstd * ga.z + be.z);
  o.w = f2bf((v.w - mean) * rstd * ga.w + be.w);
  *(ushort4*)(hn + row * CC + c4) = o;
}

// ---------------- Generic MFMA GEMM: C = (A@B + bias)*scale (+residual) ----------------
// A: M x K bf16 row-major. B: K x N fp32 row-major (converted to bf16 in LDS).
// Output either bf16 (Obf) or fp32 (Of). Tile 64x64, K-step 32, 4 waves (2x2).
#define GTM 64
#define GTN 64
#define GTK 32
#define A_LD (GTK + 8)
#define B_LD (GTK + 8)

__global__ __launch_bounds__(256) void gemm_bias_kernel(
    const unsigned short* __restrict__ A,
    const float* __restrict__ Bw,
    const float* __restrict__ bias,
    const float* __restrict__ residual,   // M x N fp32 or nullptr
    float scale,
    unsigned short* __restrict__ Obf,     // bf16 out (or nullptr)
    float* __restrict__ Of,               // f32 out (or nullptr)
    int M, int N, int K) {
  __shared__ unsigned short As[GTM][A_LD];
  __shared__ unsigned short Bs[GTN][B_LD];   // transposed: Bs[n][k]

  const int m0 = blockIdx.x * GTM;
  const int n0 = blockIdx.y * GTN;
  const int tid = threadIdx.x;
  const int wave = tid >> 6, lane = tid & 63;
  const int quad = lane >> 4, l16 = lane & 15;
  const int wm = wave >> 1, wn = wave & 1;

  f32x4 acc[2][2] = {};

  for (int k0 = 0; k0 < K; k0 += GTK) {
    __syncthreads();
    {   // stage A tile 64x32 bf16, 8 bf16 per thread, coalesced 16B
      int r  = tid >> 2;
      int ccol = (tid & 3) * 8;
      bf16x8 v = *(const bf16x8*)(A + (size_t)(m0 + r) * K + k0 + ccol);
      *(bf16x8*)(&As[r][ccol]) = v;
    }
#pragma unroll
    for (int i = 0; i < 2; i++) {  // stage B tile 32x64 fp32 -> bf16 transposed
      int linear = tid + i * 256;      // 512 float4 total (16 per k-row)
      int kk = linear >> 4;
      int nq = (linear & 15) * 4;
      float4 v = *(const float4*)(Bw + (size_t)(k0 + kk) * N + n0 + nq);
      Bs[nq + 0][kk] = f2bf(v.x);
      Bs[nq + 1][kk] = f2bf(v.y);
      Bs[nq + 2][kk] = f2bf(v.z);
      Bs[nq + 3][kk] = f2bf(v.w);
    }
    __syncthreads();

    bf16x8 af[2], bfr[2];
#pragma unroll
    for (int mt = 0; mt < 2; mt++)
      af[mt] = *(const bf16x8*)(&As[wm * 32 + mt * 16 + l16][quad * 8]);
#pragma unroll
    for (int nt = 0; nt < 2; nt++)
      bfr[nt] = *(const bf16x8*)(&Bs[wn * 32 + nt * 16 + l16][quad * 8]);
#pragma unroll
    for (int mt = 0; mt < 2; mt++)
#pragma unroll
      for (int nt = 0; nt < 2; nt++)
        acc[mt][nt] = __builtin_amdgcn_mfma_f32_16x16x32_bf16(af[mt], bfr[nt], acc[mt][nt], 0, 0, 0);
  }

#pragma unroll
  for (int mt = 0; mt < 2; mt++) {
#pragma unroll
    for (int nt = 0; nt < 2; nt++) {
      int n = n0 + wn * 32 + nt * 16 + l16;
      float bv = bias[n];
#pragma unroll
      for (int r = 0; r < 4; r++) {
        int m = m0 + wm * 32 + mt * 16 + quad * 4 + r;
        float v = (acc[mt][nt][r] + bv) * scale;
        if (residual) v += residual[(size_t)m * N + n];
        if (Obf) Obf[(size_t)m * N + n] = f2bf(v);
        else     Of [(size_t)m * N + n] = v;
      }
    }
  }
}

// ---------------- Flash attention: Br=Bc=64, D=256, 4 waves, online softmax ----------------
#define BR 64
#define BC 64
#define DD 256
#define KS_LD (DD + 8)   // 264
#define VT_LD (BC + 8)   // 72 (multiple of 8 -> 16B-aligned b128 reads)
#define PS_LD (BC + 8)

__global__ __launch_bounds__(256) void flash_attn_kernel(
    const unsigned short* __restrict__ Qg,   // (B*S, C) bf16, pre-scaled by 1/16
    const unsigned short* __restrict__ Kg,
    const unsigned short* __restrict__ Vg,
    unsigned short* __restrict__ Og) {
  // K tile and transposed-V tile share one buffer (used in disjoint phases)
  __shared__ union {
    unsigned short k[BC][KS_LD];
    unsigned short vt[DD][VT_LD];
  } kv;
  __shared__ unsigned short Ps[BR][PS_LD];

  const int b  = blockIdx.y;
  const int q0 = blockIdx.x * BR;
  const int tid = threadIdx.x;
  const int wave = tid >> 6, lane = tid & 63;
  const int quad = lane >> 4, l16 = lane & 15;

  const unsigned short* Qb = Qg + (size_t)b * SS * CC;
  const unsigned short* Kb = Kg + (size_t)b * SS * CC;
  const unsigned short* Vb = Vg + (size_t)b * SS * CC;

  // Q fragments for this wave's 16 rows, all 8 K-steps (A-layout)
  bf16x8 qf[8];
  {
    const unsigned short* qrow = Qb + (size_t)(q0 + wave * 16 + l16) * CC + quad * 8;
#pragma unroll
    for (int ks = 0; ks < 8; ks++) qf[ks] = *(const bf16x8*)(qrow + ks * 32);
  }

  f32x4 oacc[16] = {};
  float mrow[4], lrow[4];
#pragma unroll
  for (int r = 0; r < 4; r++) { mrow[r] = -1e30f; lrow[r] = 0.f; }

  for (int j0 = 0; j0 < SS; j0 += BC) {
    __syncthreads();   // previous iteration's PV reads of kv.vt done
    // ---- stage K tile (64 x 256), coalesced 16B per lane ----
#pragma unroll
    for (int i = 0; i < 8; i++) {
      int linear = tid + i * 256;
      int row = linear >> 5;
      int ch  = (linear & 31) * 8;
      *(bf16x8*)(&kv.k[row][ch]) = *(const bf16x8*)(Kb + (size_t)(j0 + row) * CC + ch);
    }
    __syncthreads();

    // ---- S = Q K^T (per-wave 16x64 strip) ----
    f32x4 sacc[4] = {};
#pragma unroll
    for (int ct = 0; ct < 4; ct++) {
#pragma unroll
      for (int ks = 0; ks < 8; ks++) {
        bf16x8 bf = *(const bf16x8*)(&kv.k[ct * 16 + l16][ks * 32 + quad * 8]);
        sacc[ct] = __builtin_amdgcn_mfma_f32_16x16x32_bf16(qf[ks], bf, sacc[ct], 0, 0, 0);
      }
    }

    // ---- online softmax (rows quad*4+r, cols across l16 and ct) ----
    float curmax[4];
#pragma unroll
    for (int r = 0; r < 4; r++) {
      float m_ = fmaxf(fmaxf(sacc[0][r], sacc[1][r]), fmaxf(sacc[2][r], sacc[3][r]));
      curmax[r] = m_;
    }
#pragma unroll
    for (int off = 1; off < 16; off <<= 1)
#pragma unroll
      for (int r = 0; r < 4; r++) curmax[r] = fmaxf(curmax[r], __shfl_xor(curmax[r], off));
    float alpha[4], rsum[4];
#pragma unroll
    for (int r = 0; r < 4; r++) {
      float nm = fmaxf(mrow[r], curmax[r]);
      alpha[r] = __expf(mrow[r] - nm);
      mrow[r] = nm;
      rsum[r] = 0.f;
    }
#pragma unroll
    for (int ct = 0; ct < 4; ct++)
#pragma unroll
      for (int r = 0; r < 4; r++) {
        float p = __expf(sacc[ct][r] - mrow[r]);
        rsum[r] += p;
        Ps[wave * 16 + quad * 4 + r][ct * 16 + l16] = f2bf(p);
      }
#pragma unroll
    for (int off = 1; off < 16; off <<= 1)
#pragma unroll
      for (int r = 0; r < 4; r++) rsum[r] += __shfl_xor(rsum[r], off);
#pragma unroll
    for (int r = 0; r < 4; r++) lrow[r] = lrow[r] * alpha[r] + rsum[r];
#pragma unroll
    for (int nt = 0; nt < 16; nt++)
#pragma unroll
      for (int r = 0; r < 4; r++) oacc[nt][r] *= alpha[r];

    __syncthreads();   // all waves done reading kv.k
    // ---- stage V tile transposed: kv.vt[c][t] (lanes vary t -> conflict-free LDS writes) ----
#pragma unroll
    for (int i = 0; i < 8; i++) {
      int linear = tid + i * 256;
      int t  = linear & 63;
      int ch = (linear >> 6) * 8;
      bf16x8 v = *(const bf16x8*)(Vb + (size_t)(j0 + t) * CC + ch);
#pragma unroll
      for (int jj = 0; jj < 8; jj++) kv.vt[ch + jj][t] = v[jj];
    }
    __syncthreads();

    // ---- O += P V ----
    bf16x8 pf[2];
#pragma unroll
    for (int kt = 0; kt < 2; kt++)
      pf[kt] = *(const bf16x8*)(&Ps[wave * 16 + l16][kt * 32 + quad * 8]);
#pragma unroll
    for (int nt = 0; nt < 16; nt++) {
#pragma unroll
      for (int kt = 0; kt < 2; kt++) {
        bf16x8 vf = *(const bf16x8*)(&kv.vt[nt * 16 + l16][kt * 32 + quad * 8]);
        oacc[nt] = __builtin_amdgcn_mfma_f32_16x16x32_bf16(pf[kt], vf, oacc[nt], 0, 0, 0);
      }
    }
  }

  // ---- epilogue: O / l -> bf16 ----
#pragma unroll
  for (int r = 0; r < 4; r++) lrow[r] = 1.f / lrow[r];
#pragma unroll
  for (int nt = 0; nt < 16; nt++)
#pragma unroll
    for (int r = 0; r < 4; r++) {
      size_t row = (size_t)b * SS + q0 + wave * 16 + quad * 4 + r;
      Og[row * CC + nt * 16 + l16] = f2bf(oacc[nt][r] * lrow[r]);
    }
}

// ---------------- launch ----------------
extern "C" void kernel_launch(void* const* d_in, const int* in_sizes, int n_in,
                              void* d_out, int out_size, void* d_ws, size_t ws_size,
                              hipStream_t stream) {
  const float* x   = (const float*)d_in[0];
  const float* gsc = (const float*)d_in[1];
  const float* gbi = (const float*)d_in[2];
  const float* wq  = (const float*)d_in[3];
  const float* bq  = (const float*)d_in[4];
  const float* wk  = (const float*)d_in[5];
  const float* bk  = (const float*)d_in[6];
  const float* wv  = (const float*)d_in[7];
  const float* bv  = (const float*)d_in[8];
  const float* wo  = (const float*)d_in[9];
  const float* bo  = (const float*)d_in[10];
  float* out = (float*)d_out;

  // workspace layout (~84 MB): stats | hn | q | k | v | attn_out  (all bf16 except stats)
  char* ws = (char*)d_ws;
  const size_t MAT = (size_t)MTOT * CC;  // 8.39M elements
  float* stats        = (float*)ws;
  unsigned short* hn  = (unsigned short*)(ws + 4096);
  unsigned short* q   = hn + MAT;
  unsigned short* k   = q  + MAT;
  unsigned short* v   = k  + MAT;
  unsigned short* ao  = v  + MAT;

  gn_stats_kernel<<<NB * NG, 256, 0, stream>>>(x, stats);
  gn_norm_kernel<<<(int)(MAT / 4 / 256), 256, 0, stream>>>(x, stats, gsc, gbi, hn);

  dim3 gg(MTOT / GTM, CC / GTN);  // (512, 4)
  gemm_bias_kernel<<<gg, 256, 0, stream>>>(hn, wq, bq, nullptr, 1.f / 16.f, q, nullptr, MTOT, CC, CC);
  gemm_bias_kernel<<<gg, 256, 0, stream>>>(hn, wk, bk, nullptr, 1.f,        k, nullptr, MTOT, CC, CC);
  gemm_bias_kernel<<<gg, 256, 0, stream>>>(hn, wv, bv, nullptr, 1.f,        v, nullptr, MTOT, CC, CC);

  flash_attn_kernel<<<dim3(SS / BR, NB), 256, 0, stream>>>(q, k, v, ao);

  gemm_bias_kernel<<<gg, 256, 0, stream>>>(ao, wo, bo, x, 1.f, nullptr, out, MTOT, CC, CC);
}

// Round 2
// 461.705 us; speedup vs baseline: 1.8158x; 1.8158x over previous
//
#include <hip/hip_runtime.h>

// Problem constants (B,H,W,C = 8,64,64,256; S = H*W)
#define NB   8
#define SS   4096
#define CC   256
#define NG   32
#define CPG  8
#define EPSV 1e-6f
#define MTOT (NB * SS)   // 32768 rows

typedef short bf16x8 __attribute__((ext_vector_type(8)));
typedef float f32x4  __attribute__((ext_vector_type(4)));

__device__ __forceinline__ unsigned short f2bf(float f) {
  unsigned int u = __builtin_bit_cast(unsigned int, f);
  u = (u + 0x7FFFu + ((u >> 16) & 1u)) >> 16;
  return (unsigned short)u;
}

// ---------------- GroupNorm: stats (block per (b, group)) ----------------
__global__ __launch_bounds__(256) void gn_stats_kernel(const float* __restrict__ x,
                                                       float* __restrict__ stats) {
  int bg = blockIdx.x;           // 0..255
  int b = bg >> 5, g = bg & 31;
  const float* base = x + (size_t)b * SS * CC + g * CPG;
  float s = 0.f, ss = 0.f;
  for (int pos = threadIdx.x; pos < SS; pos += 256) {
    const float4* p = (const float4*)(base + (size_t)pos * CC);
    float4 a = p[0];
    float4 c = p[1];
    s  += (a.x + a.y) + (a.z + a.w) + (c.x + c.y) + (c.z + c.w);
    ss += (a.x*a.x + a.y*a.y) + (a.z*a.z + a.w*a.w)
        + (c.x*c.x + c.y*c.y) + (c.z*c.z + c.w*c.w);
  }
#pragma unroll
  for (int off = 32; off >= 1; off >>= 1) {
    s  += __shfl_xor(s, off);
    ss += __shfl_xor(ss, off);
  }
  __shared__ float rs[4], rss[4];
  int wv = threadIdx.x >> 6;
  if ((threadIdx.x & 63) == 0) { rs[wv] = s; rss[wv] = ss; }
  __syncthreads();
  if (threadIdx.x == 0) {
    float ts  = (rs[0] + rs[1]) + (rs[2] + rs[3]);
    float tss = (rss[0] + rss[1]) + (rss[2] + rss[3]);
    const float inv = 1.f / (float)(SS * CPG);
    float mean = ts * inv;
    float var  = tss * inv - mean * mean;
    stats[bg * 2]     = mean;
    stats[bg * 2 + 1] = rsqrtf(var + EPSV);
  }
}

// ---------------- GroupNorm: normalize -> hn (bf16) ----------------
__global__ __launch_bounds__(256) void gn_norm_kernel(const float* __restrict__ x,
                                                      const float* __restrict__ stats,
                                                      const float* __restrict__ gamma,
                                                      const float* __restrict__ beta,
                                                      unsigned short* __restrict__ hn) {
  int i4 = blockIdx.x * 256 + threadIdx.x;      // each handles 4 channels
  int c4 = (i4 & 63) * 4;                       // 64 float4 per row
  size_t row = (size_t)(i4 >> 6);               // b*S + s
  int b = (int)(row >> 12);
  int sidx = (b * NG + (c4 >> 3)) * 2;
  float mean = stats[sidx], rstd = stats[sidx + 1];
  float4 v  = *(const float4*)(x + row * CC + c4);
  float4 ga = *(const float4*)(gamma + c4);
  float4 be = *(const float4*)(beta + c4);
  ushort4 o;
  o.x = f2bf((v.x - mean) * rstd * ga.x + be.x);
  o.y = f2bf((v.y - mean) * rstd * ga.y + be.y);
  o.z = f2bf((v.z - mean) * rstd * ga.z + be.z);
  o.w = f2bf((v.w - mean) * rstd * ga.w + be.w);
  *(ushort4*)(hn + row * CC + c4) = o;
}

// ---------------- Tiled MFMA GEMM pieces (64x64 tile, K-step 32, 4 waves) ----------------
#define GTM 64
#define GTN 64
#define GTK 32
#define A_LD (GTK + 8)
#define B_LD (GTK + 8)

// QKV fused: z-slice picks {wq,wk,wv}. V output is written TRANSPOSED (B,C,S)
// so the flash kernel can stage V^T tiles with vector LDS writes.
__global__ __launch_bounds__(256) void qkv_gemm_kernel(
    const unsigned short* __restrict__ A,
    const float* __restrict__ wq, const float* __restrict__ bq,
    const float* __restrict__ wk, const float* __restrict__ bk,
    const float* __restrict__ wv, const float* __restrict__ bv,
    unsigned short* __restrict__ qo,
    unsigned short* __restrict__ ko,
    unsigned short* __restrict__ vt) {
  __shared__ unsigned short As[GTM][A_LD];
  __shared__ unsigned short Bs[GTN][B_LD];   // transposed: Bs[n][k]

  const int which = blockIdx.z;
  const float* Bw   = (which == 0) ? wq : (which == 1) ? wk : wv;
  const float* bias = (which == 0) ? bq : (which == 1) ? bk : bv;
  const float scale = (which == 0) ? (1.f / 16.f) : 1.f;   // fold 1/sqrt(C) into Q

  const int m0 = blockIdx.x * GTM;
  const int n0 = blockIdx.y * GTN;
  const int tid = threadIdx.x;
  const int wave = tid >> 6, lane = tid & 63;
  const int quad = lane >> 4, l16 = lane & 15;
  const int wm = wave >> 1, wn = wave & 1;

  f32x4 acc[2][2] = {};

  for (int k0 = 0; k0 < CC; k0 += GTK) {
    __syncthreads();
    {   // stage A tile 64x32 bf16
      int r  = tid >> 2;
      int ccol = (tid & 3) * 8;
      bf16x8 v = *(const bf16x8*)(A + (size_t)(m0 + r) * CC + k0 + ccol);
      *(bf16x8*)(&As[r][ccol]) = v;
    }
#pragma unroll
    for (int i = 0; i < 2; i++) {  // stage B tile 32x64 fp32 -> bf16 transposed
      int linear = tid + i * 256;
      int kk = linear >> 4;
      int nq = (linear & 15) * 4;
      float4 v = *(const float4*)(Bw + (size_t)(k0 + kk) * CC + n0 + nq);
      Bs[nq + 0][kk] = f2bf(v.x);
      Bs[nq + 1][kk] = f2bf(v.y);
      Bs[nq + 2][kk] = f2bf(v.z);
      Bs[nq + 3][kk] = f2bf(v.w);
    }
    __syncthreads();

    bf16x8 af[2], bfr[2];
#pragma unroll
    for (int mt = 0; mt < 2; mt++)
      af[mt] = *(const bf16x8*)(&As[wm * 32 + mt * 16 + l16][quad * 8]);
#pragma unroll
    for (int nt = 0; nt < 2; nt++)
      bfr[nt] = *(const bf16x8*)(&Bs[wn * 32 + nt * 16 + l16][quad * 8]);
#pragma unroll
    for (int mt = 0; mt < 2; mt++)
#pragma unroll
      for (int nt = 0; nt < 2; nt++)
        acc[mt][nt] = __builtin_amdgcn_mfma_f32_16x16x32_bf16(af[mt], bfr[nt], acc[mt][nt], 0, 0, 0);
  }

#pragma unroll
  for (int mt = 0; mt < 2; mt++) {
#pragma unroll
    for (int nt = 0; nt < 2; nt++) {
      int n = n0 + wn * 32 + nt * 16 + l16;
      float bv = bias[n];
      int mbase = m0 + wm * 32 + mt * 16 + quad * 4;
      if (which < 2) {
        unsigned short* out = (which == 0) ? qo : ko;
#pragma unroll
        for (int r = 0; r < 4; r++)
          out[(size_t)(mbase + r) * CC + n] = f2bf((acc[mt][nt][r] + bv) * scale);
      } else {
        int bb = mbase >> 12;        // all 64 tile rows share one batch (4096 % 64 == 0)
        ushort4 o4;
        o4.x = f2bf(acc[mt][nt][0] + bv);
        o4.y = f2bf(acc[mt][nt][1] + bv);
        o4.z = f2bf(acc[mt][nt][2] + bv);
        o4.w = f2bf(acc[mt][nt][3] + bv);
        *(ushort4*)(vt + (size_t)bb * CC * SS + (size_t)n * SS + (mbase & 4095)) = o4;
      }
    }
  }
}

// Final projection: out = ao @ wo + bo + x  (fp32 out)
__global__ __launch_bounds__(256) void out_gemm_kernel(
    const unsigned short* __restrict__ A,
    const float* __restrict__ Bw,
    const float* __restrict__ bias,
    const float* __restrict__ residual,
    float* __restrict__ Of) {
  __shared__ unsigned short As[GTM][A_LD];
  __shared__ unsigned short Bs[GTN][B_LD];

  const int m0 = blockIdx.x * GTM;
  const int n0 = blockIdx.y * GTN;
  const int tid = threadIdx.x;
  const int wave = tid >> 6, lane = tid & 63;
  const int quad = lane >> 4, l16 = lane & 15;
  const int wm = wave >> 1, wn = wave & 1;

  f32x4 acc[2][2] = {};

  for (int k0 = 0; k0 < CC; k0 += GTK) {
    __syncthreads();
    {
      int r  = tid >> 2;
      int ccol = (tid & 3) * 8;
      bf16x8 v = *(const bf16x8*)(A + (size_t)(m0 + r) * CC + k0 + ccol);
      *(bf16x8*)(&As[r][ccol]) = v;
    }
#pragma unroll
    for (int i = 0; i < 2; i++) {
      int linear = tid + i * 256;
      int kk = linear >> 4;
      int nq = (linear & 15) * 4;
      float4 v = *(const float4*)(Bw + (size_t)(k0 + kk) * CC + n0 + nq);
      Bs[nq + 0][kk] = f2bf(v.x);
      Bs[nq + 1][kk] = f2bf(v.y);
      Bs[nq + 2][kk] = f2bf(v.z);
      Bs[nq + 3][kk] = f2bf(v.w);
    }
    __syncthreads();

    bf16x8 af[2], bfr[2];
#pragma unroll
    for (int mt = 0; mt < 2; mt++)
      af[mt] = *(const bf16x8*)(&As[wm * 32 + mt * 16 + l16][quad * 8]);
#pragma unroll
    for (int nt = 0; nt < 2; nt++)
      bfr[nt] = *(const bf16x8*)(&Bs[wn * 32 + nt * 16 + l16][quad * 8]);
#pragma unroll
    for (int mt = 0; mt < 2; mt++)
#pragma unroll
      for (int nt = 0; nt < 2; nt++)
        acc[mt][nt] = __builtin_amdgcn_mfma_f32_16x16x32_bf16(af[mt], bfr[nt], acc[mt][nt], 0, 0, 0);
  }

#pragma unroll
  for (int mt = 0; mt < 2; mt++) {
#pragma unroll
    for (int nt = 0; nt < 2; nt++) {
      int n = n0 + wn * 32 + nt * 16 + l16;
      float bv = bias[n];
#pragma unroll
      for (int r = 0; r < 4; r++) {
        int m = m0 + wm * 32 + mt * 16 + quad * 4 + r;
        Of[(size_t)m * CC + n] = acc[mt][nt][r] + bv + residual[(size_t)m * CC + n];
      }
    }
  }
}

// ---------------- Flash attention: Br=Bc=64, D=256, 4 waves, online softmax ----------------
// LDS layout: XOR-swizzled, unpadded. Element (row, 16B-chunk c) lives at
// chunk (c ^ (row & 7)) — every b128 fragment read/write is a balanced
// permutation over banks (<=2 lanes/bank = free per m136).
#define BR 64
#define BC 64

__global__ __launch_bounds__(256, 2) void flash_attn_kernel(
    const unsigned short* __restrict__ Qg,   // (B,S,C) bf16, pre-scaled by 1/16
    const unsigned short* __restrict__ Kg,   // (B,S,C)
    const unsigned short* __restrict__ Vtg,  // (B,C,S)  pre-transposed by V GEMM
    unsigned short* __restrict__ Og) {
  __shared__ unsigned short kv[BC * CC];     // K tile (64x256) / Vt tile (256x64), phases disjoint
  __shared__ unsigned short Ps[BR * BC];     // P tile (per-wave private strips)

  const int b  = blockIdx.y;
  const int q0 = blockIdx.x * BR;
  const int tid = threadIdx.x;
  const int wave = tid >> 6, lane = tid & 63;
  const int quad = lane >> 4, l16 = lane & 15;

  const unsigned short* Qb  = Qg  + (size_t)b * SS * CC;
  const unsigned short* Kb  = Kg  + (size_t)b * SS * CC;
  const unsigned short* Vtb = Vtg + (size_t)b * CC * SS;

  // staging index split (K: 2048 b128 chunks; Vt: 2048 b128 chunks)
  const int krow   = tid >> 5;   // + 8*i
  const int kchunk = tid & 31;
  const int vc     = tid >> 3;   // + 32*i
  const int vchunk = tid & 7;

  // Q fragments: wave's 16 rows, all 8 K-steps (A-layout), held in regs
  bf16x8 qf[8];
  {
    const unsigned short* qrow = Qb + (size_t)(q0 + wave * 16 + l16) * CC + quad * 8;
#pragma unroll
    for (int ks = 0; ks < 8; ks++) qf[ks] = *(const bf16x8*)(qrow + ks * 32);
  }

  f32x4 oacc[16] = {};
  float mrow[4], lrow[4];
#pragma unroll
  for (int r = 0; r < 4; r++) { mrow[r] = -1e30f; lrow[r] = 0.f; }

  // software pipeline: stg holds K(j) at loop top, then Vt(j), then K(j+1)
  bf16x8 stg[8];
#pragma unroll
  for (int i = 0; i < 8; i++)
    stg[i] = *(const bf16x8*)(Kb + (size_t)(krow + i * 8) * CC + kchunk * 8);

  for (int j0 = 0; j0 < SS; j0 += BC) {
    __syncthreads();   // prior PV reads of kv (Vt) done
    // ---- K regs -> LDS (swizzled) ----
#pragma unroll
    for (int i = 0; i < 8; i++) {
      int row = krow + i * 8;
      *(bf16x8*)(&kv[row * 256 + ((kchunk ^ (row & 7)) << 3)]) = stg[i];
    }
    __syncthreads();
    // ---- issue Vt(j0) global loads (in flight during QK+softmax) ----
#pragma unroll
    for (int i = 0; i < 8; i++) {
      int c = vc + i * 32;
      stg[i] = *(const bf16x8*)(Vtb + (size_t)c * SS + j0 + vchunk * 8);
    }

    // ---- S = Q K^T (per-wave 16x64 strip) ----
    f32x4 sacc[4] = {};
#pragma unroll
    for (int ct = 0; ct < 4; ct++) {
      int row = ct * 16 + l16;
#pragma unroll
      for (int ks = 0; ks < 8; ks++) {
        int chunk = ks * 4 + quad;
        bf16x8 bf = *(const bf16x8*)(&kv[row * 256 + ((chunk ^ (l16 & 7)) << 3)]);
        sacc[ct] = __builtin_amdgcn_mfma_f32_16x16x32_bf16(qf[ks], bf, sacc[ct], 0, 0, 0);
      }
    }

    // ---- online softmax (rows quad*4+r, cols across l16 and ct) ----
    float curmax[4];
#pragma unroll
    for (int r = 0; r < 4; r++)
      curmax[r] = fmaxf(fmaxf(sacc[0][r], sacc[1][r]), fmaxf(sacc[2][r], sacc[3][r]));
#pragma unroll
    for (int off = 1; off < 16; off <<= 1)
#pragma unroll
      for (int r = 0; r < 4; r++) curmax[r] = fmaxf(curmax[r], __shfl_xor(curmax[r], off));
    float alpha[4], rsum[4];
#pragma unroll
    for (int r = 0; r < 4; r++) {
      float nm = fmaxf(mrow[r], curmax[r]);
      alpha[r] = __expf(mrow[r] - nm);
      mrow[r] = nm;
      rsum[r] = 0.f;
    }
#pragma unroll
    for (int ct = 0; ct < 4; ct++)
#pragma unroll
      for (int r = 0; r < 4; r++) {
        float p = __expf(sacc[ct][r] - mrow[r]);
        rsum[r] += p;
        int m = wave * 16 + quad * 4 + r;
        int col = ct * 16 + l16;
        Ps[m * 64 + (((col >> 3) ^ (m & 7)) << 3) + (col & 7)] = f2bf(p);
      }
#pragma unroll
    for (int off = 1; off < 16; off <<= 1)
#pragma unroll
      for (int r = 0; r < 4; r++) rsum[r] += __shfl_xor(rsum[r], off);
#pragma unroll
    for (int r = 0; r < 4; r++) lrow[r] = lrow[r] * alpha[r] + rsum[r];
#pragma unroll
    for (int nt = 0; nt < 16; nt++)
#pragma unroll
      for (int r = 0; r < 4; r++) oacc[nt][r] *= alpha[r];

    __syncthreads();   // all waves done reading kv (K)
    // ---- Vt regs -> LDS (swizzled) ----
#pragma unroll
    for (int i = 0; i < 8; i++) {
      int c = vc + i * 32;
      *(bf16x8*)(&kv[c * 64 + ((vchunk ^ (c & 7)) << 3)]) = stg[i];
    }
    __syncthreads();
    // ---- issue K(j0+BC) global loads (in flight during PV) ----
    {
      int jn = (j0 + BC < SS) ? (j0 + BC) : j0;
#pragma unroll
      for (int i = 0; i < 8; i++)
        stg[i] = *(const bf16x8*)(Kb + (size_t)(jn + krow + i * 8) * CC + kchunk * 8);
    }

    // ---- O += P V ----
    bf16x8 pf[2];
#pragma unroll
    for (int kt = 0; kt < 2; kt++) {
      int m = wave * 16 + l16;
      int chunk = kt * 4 + quad;
      pf[kt] = *(const bf16x8*)(&Ps[m * 64 + ((chunk ^ (l16 & 7)) << 3)]);
    }
#pragma unroll
    for (int nt = 0; nt < 16; nt++) {
      int c = nt * 16 + l16;
#pragma unroll
      for (int kt = 0; kt < 2; kt++) {
        int chunk = kt * 4 + quad;
        bf16x8 vf = *(const bf16x8*)(&kv[c * 64 + ((chunk ^ (l16 & 7)) << 3)]);
        oacc[nt] = __builtin_amdgcn_mfma_f32_16x16x32_bf16(pf[kt], vf, oacc[nt], 0, 0, 0);
      }
    }
  }

  // ---- epilogue: O / l -> bf16 ----
#pragma unroll
  for (int r = 0; r < 4; r++) lrow[r] = 1.f / lrow[r];
#pragma unroll
  for (int nt = 0; nt < 16; nt++)
#pragma unroll
    for (int r = 0; r < 4; r++) {
      size_t row = (size_t)b * SS + q0 + wave * 16 + quad * 4 + r;
      Og[row * CC + nt * 16 + l16] = f2bf(oacc[nt][r] * lrow[r]);
    }
}

// ---------------- launch ----------------
extern "C" void kernel_launch(void* const* d_in, const int* in_sizes, int n_in,
                              void* d_out, int out_size, void* d_ws, size_t ws_size,
                              hipStream_t stream) {
  const float* x   = (const float*)d_in[0];
  const float* gsc = (const float*)d_in[1];
  const float* gbi = (const float*)d_in[2];
  const float* wq  = (const float*)d_in[3];
  const float* bq  = (const float*)d_in[4];
  const float* wk  = (const float*)d_in[5];
  const float* bk  = (const float*)d_in[6];
  const float* wv  = (const float*)d_in[7];
  const float* bv  = (const float*)d_in[8];
  const float* wo  = (const float*)d_in[9];
  const float* bo  = (const float*)d_in[10];
  float* out = (float*)d_out;

  // workspace layout (~84 MB): stats | hn | q | k | vt | attn_out
  char* ws = (char*)d_ws;
  const size_t MAT = (size_t)MTOT * CC;
  float* stats        = (float*)ws;
  unsigned short* hn  = (unsigned short*)(ws + 4096);
  unsigned short* q   = hn + MAT;
  unsigned short* k   = q  + MAT;
  unsigned short* vt  = k  + MAT;
  unsigned short* ao  = vt + MAT;

  gn_stats_kernel<<<NB * NG, 256, 0, stream>>>(x, stats);
  gn_norm_kernel<<<(int)(MAT / 4 / 256), 256, 0, stream>>>(x, stats, gsc, gbi, hn);

  qkv_gemm_kernel<<<dim3(MTOT / GTM, CC / GTN, 3), 256, 0, stream>>>(
      hn, wq, bq, wk, bk, wv, bv, q, k, vt);

  flash_attn_kernel<<<dim3(SS / BR, NB), 256, 0, stream>>>(q, k, vt, ao);

  out_gemm_kernel<<<dim3(MTOT / GTM, CC / GTN), 256, 0, stream>>>(ao, wo, bo, x, out);
}